// Round 9
// baseline (488.876 us; speedup 1.0000x reference)
//
#include <hip/hip_runtime.h>
#include <cstdint>
#include <cstddef>

#define NN 8192
#define FIN 256
#define FOUT 128
#define SLOPE 0.2f
#define SHIFT 8.0f

typedef float f32x4 __attribute__((ext_vector_type(4)));
typedef __bf16 bf16x8 __attribute__((ext_vector_type(8)));
typedef int i32x4 __attribute__((ext_vector_type(4)));
typedef unsigned int u32x4 __attribute__((ext_vector_type(4)));

__device__ __forceinline__ unsigned short f2bf(float f) {
  return __builtin_bit_cast(unsigned short, (__bf16)f);
}

// async global->LDS DMA; LDS dest = wave-uniform base + lane*16; per-lane src
__device__ __forceinline__ void async_cp16(void* lds, const void* g) {
  __builtin_amdgcn_global_load_lds(
      (const __attribute__((address_space(1))) void*)g,
      (__attribute__((address_space(3))) void*)lds, 16, 0, 0);
}

// ---------------------------------------------------------------------------
// Kernel A: h = x @ W (fp32 acc) -> ht[FOUT][NN] bf16 (transposed), fused
// s-reductions + exp tables. Unchanged.
// ---------------------------------------------------------------------------
__global__ __launch_bounds__(256, 4) void k_hw(const float* __restrict__ x,
                                               const float* __restrict__ W,
                                               const float* __restrict__ a1,
                                               const float* __restrict__ a2,
                                               unsigned short* __restrict__ ht,
                                               float* __restrict__ Etab,
                                               unsigned short* __restrict__ FbfF,
                                               unsigned short* __restrict__ FbfF2) {
  __shared__ float xs[8][256];
  __shared__ unsigned short tile[128][8];   // [f][row]
  const int tid = threadIdx.x;
  const int rowbase = blockIdx.x * 8;

  #pragma unroll
  for (int it = 0; it < 2; ++it) {
    int fi = it * 1024 + tid * 4;
    int r = fi >> 8, k = fi & 255;
    *(f32x4*)&xs[r][k] = *(const f32x4*)(x + (size_t)(rowbase + r) * FIN + k);
  }
  __syncthreads();

  const int r = tid >> 5;    // 0..7
  const int cg = tid & 31;   // cols cg*4..cg*4+3
  f32x4 acc = {0.f, 0.f, 0.f, 0.f};

  #pragma unroll 8
  for (int k = 0; k < FIN; ++k) {
    f32x4 wv = *(const f32x4*)(W + k * FOUT + cg * 4);
    float xv = xs[r][k];
    acc[0] += xv * wv[0];
    acc[1] += xv * wv[1];
    acc[2] += xv * wv[2];
    acc[3] += xv * wv[3];
  }

  #pragma unroll
  for (int c = 0; c < 4; ++c) tile[cg * 4 + c][r] = f2bf(acc[c]);

  f32x4 av1 = *(const f32x4*)(a1 + cg * 4);
  f32x4 av2 = *(const f32x4*)(a2 + cg * 4);
  float s1 = acc[0] * av1[0] + acc[1] * av1[1] + acc[2] * av1[2] + acc[3] * av1[3];
  float s2 = acc[0] * av2[0] + acc[1] * av2[1] + acc[2] * av2[2] + acc[3] * av2[3];
  #pragma unroll
  for (int off = 16; off > 0; off >>= 1) {
    s1 += __shfl_xor(s1, off, 64);
    s2 += __shfl_xor(s2, off, 64);
  }
  if (cg == 0) {
    const int row = rowbase + r;
    float c0 = s1 + SHIFT;
    float c = fmaxf(c0, SLOPE * c0);
    Etab[(size_t)row * 2]     = __expf(s1 - c);
    Etab[(size_t)row * 2 + 1] = __expf(SLOPE * s1 - c);
    FbfF[row]  = f2bf(__expf(s2));
    FbfF2[row] = f2bf(__expf(SLOPE * s2));
  }
  __syncthreads();

  if (tid < 128) {
    u32x4 v = *(const u32x4*)&tile[tid][0];
    *(u32x4*)(ht + (size_t)tid * NN + rowbase) = v;
  }
}

// ---------------------------------------------------------------------------
// Kernel B: fused masked-softmax aggregation, v17 = DIAGNOSTIC PROBE.
// Five blind rounds (v12-v16): every scheduling/staging attack moved dur by
// <= +-12 us while the cost model failed 5x (v10's 164 us matched the per-CU
// ingest model exactly; v14's inferred ~97 us is 5x above its ~18 us model).
// k_gat has been invisible in rocprof top-5 (sits under the 158 us workspace
// poison fills) since R4. This round RUNS THE CHUNK LOOP TWICE WITHOUT
// RESETTING acc/den: num and den both double -> num/den preserved to fp32
// rounding (~1e-6 abs vs 2e-3 margin); nothing is DCE-able (accumulators
// carry); regime is genuine (adj 268 MB > L3, pass 2 still streams).
// k_gat ~280 us -> tops the dispatch table -> full counters.
// Pre-committed branch on the counters:
//   VALUBusy>=55%            -> VALU-bound af build -> cheapen weight path
//   VALUBusy<35% & Mfma<10%  -> latency/phase-bound -> fatter phases
//   FETCH >> 600 MB          -> address amplification bug in adj loads
//   LDS_BANK_CONFLICT large  -> swizzle bug
// Next round reverts the repeat. Structure = v15 verbatim otherwise.
// ---------------------------------------------------------------------------
__global__ __launch_bounds__(512, 4) void k_gat(const int* __restrict__ adj,
                                                const unsigned short* __restrict__ ht,
                                                const float* __restrict__ Etab,
                                                const unsigned short* __restrict__ FbfF,
                                                const unsigned short* __restrict__ FbfF2,
                                                float* __restrict__ part,
                                                float* __restrict__ denp) {
  __shared__ unsigned short sH[2][128 * 64]; // 32 KB : ht, slot s holds group s^(f&7)
  __shared__ unsigned int sAp[2][128][2];    // 2 KB  : [buf][local row][word]
  __shared__ unsigned short sF[2][128];      // 512 B : [0,64)=F plane, [64,128)=F2

  const int tid = threadIdx.x;
  const int wave = tid >> 6;                 // 0..7, owns rows 16w..16w+15
  const int lane = tid & 63;
  const int quad = lane >> 4;
  const int m = lane & 15;                   // A-row label within wave's 16
  const int rowbase = (int)(blockIdx.x >> 3) * 128;
  const int colbase = (int)(blockIdx.x & 7) * 1024;
  const int CB = (int)(blockIdx.x & 7);
  const int row = rowbase + wave * 16 + m;

  // ---- runtime layout probes (exact in bf16/fp32) ----
  bf16x8 pm, pinv, pones;
  #pragma unroll
  for (int jj = 0; jj < 8; ++jj) {
    pm[jj] = (__bf16)(float)m;
    pinv[jj] = (__bf16)0.03125f;
    pones[jj] = (__bf16)1.0f;
  }
  f32x4 z = {0.f, 0.f, 0.f, 0.f};
  f32x4 rp = __builtin_amdgcn_mfma_f32_16x16x32_bf16(pm, pinv, z, 0, 0, 0);
  f32x4 cp = __builtin_amdgcn_mfma_f32_16x16x32_bf16(pinv, pm, z, 0, 0, 0);
  int rowmap[4], colmap[4];
  #pragma unroll
  for (int r = 0; r < 4; ++r) {
    rowmap[r] = ((int)(rp[r] + 0.5f)) & 15;
    colmap[r] = ((int)(cp[r] + 0.5f)) & 15;
  }

  const float E  = Etab[(size_t)row * 2];
  const float E2 = Etab[(size_t)row * 2 + 1];

  f32x4 acc[8];
  #pragma unroll
  for (int t = 0; t < 8; ++t) acc[t] = z;
  f32x4 den = z;

  // ---- adj raw source + register pipeline ----
  const int* adjRow = adj + (size_t)(rowbase + wave * 16) * NN + colbase + lane;
  int aregs[16];
  auto loadA = [&](int c) {            // 16 coalesced scalar loads (256 B/instr)
    #pragma unroll
    for (int r = 0; r < 16; ++r)
      aregs[r] = adjRow[(size_t)r * NN + c * 64];
  };
  auto packA = [&](int b) {            // ballot-pack regs -> sAp[b]
    #pragma unroll
    for (int r = 0; r < 16; ++r) {
      const unsigned long long mk = __ballot(aregs[r] != 0);
      if (lane == 0)
        *(unsigned long long*)&sAp[b][wave * 16 + r][0] = mk;
    }
  };

  // ---- ht / F DMA source pointers ----
  const unsigned short* srcH[2];
  #pragma unroll
  for (int il = 0; il < 2; ++il) {
    const int i = wave * 2 + il;
    const int f = i * 8 + (lane >> 3);
    const int g = (lane & 7) ^ (lane >> 3);
    srcH[il] = ht + (size_t)f * NN + colbase + g * 8;
  }
  const unsigned short* srcF = nullptr;
  if (wave == 1) {
    srcF = (lane < 8) ? (FbfF + colbase + lane * 8)
                      : (FbfF2 + colbase + (lane - 8) * 8);
  }

  auto stage = [&](int b, int c) {
    #pragma unroll
    for (int il = 0; il < 2; ++il)
      async_cp16(&sH[b][(wave * 2 + il) * 512], srcH[il] + c * 64);
    if (wave == 1 && lane < 16) async_cp16(&sF[b][0], srcF + c * 64);
  };

  auto compute = [&](int cs) {
    #pragma unroll
    for (int k32 = 0; k32 < 2; ++k32) {
      const unsigned int word = sAp[cs][wave * 16 + m][k32];
      const unsigned int byt = (word >> (quad * 8)) & 0xffu;
      const int jl = k32 * 32 + quad * 8;
      u32x4 Fq = *(const u32x4*)&sF[cs][jl];        // 8 bf16 F
      u32x4 Gq = *(const u32x4*)&sF[cs][64 + jl];   // 8 bf16 F2

      bf16x8 af;
      #pragma unroll
      for (int p = 0; p < 4; ++p) {
        const unsigned fp = Fq[p], gp = Gq[p];
        const float Flo = __builtin_bit_cast(float, fp << 16);
        const float Fhi = __builtin_bit_cast(float, fp & 0xffff0000u);
        const float Glo = __builtin_bit_cast(float, gp << 16);
        const float Ghi = __builtin_bit_cast(float, gp & 0xffff0000u);
        const float wlo = fmaxf(E * Flo, E2 * Glo);
        const float whi = fmaxf(E * Fhi, E2 * Ghi);
        af[p * 2]     = (byt & (1u << (p * 2)))     ? (__bf16)wlo : (__bf16)0.0f;
        af[p * 2 + 1] = (byt & (1u << (p * 2 + 1))) ? (__bf16)whi : (__bf16)0.0f;
      }

      // ht frags: tile t, slot s = (4k32+quad) ^ (m&7); same af for all 8 t
      const int s0 = (k32 * 4 + quad) ^ (m & 7);
      #pragma unroll
      for (int t = 0; t < 8; ++t) {
        bf16x8 bt = __builtin_bit_cast(bf16x8,
            *(const u32x4*)&sH[cs][(t * 16 + m) * 64 + s0 * 8]);
        acc[t] = __builtin_amdgcn_mfma_f32_16x16x32_bf16(af, bt, acc[t], 0, 0, 0);
      }
      den = __builtin_amdgcn_mfma_f32_16x16x32_bf16(af, pones, den, 0, 0, 0);
    }
  };

  // ==== DIAGNOSTIC: run the full staged loop TWICE, accumulating both ====
  // passes into acc/den (num and den double -> num/den unchanged to fp32
  // rounding). Rep boundary is race-free: chunk-15 readers use buf 1; the
  // next rep's prologue writes buf 0; the c=15 barrier guarantees all waves
  // are past compute(14).
  #pragma unroll 1
  for (int rep = 0; rep < 2; ++rep) {
    // prologue: pack chunk 0, preload regs for chunk 1, DMA chunk 0
    loadA(0);       // compiler inserts the vmcnt wait before the ballots
    packA(0);
    loadA(1);
    stage(0, 0);

    // 16 chunks; per phase: barrier (drains DMA(c) + loads(c+1)) ->
    // ballots(c+1) -> issue loads(c+2) early -> DMA(c+1) -> compute(c).
    #pragma unroll 1
    for (int c = 0; c < 16; ++c) {
      const int cs = c & 1, ns = cs ^ 1;
      __syncthreads();
      if (c + 1 < 16) {
        packA(ns);                          // regs -> sAp[ns] (chunk c+1)
        loadA(c + 2 < 16 ? c + 2 : 15);     // issue next loads (dead at tail)
        stage(ns, c + 1);                   // ht/F DMA chunk c+1
      }
      compute(cs);                          // chunk c
    }
  }

  // ---- epilogue: coalesced partial stores via LDS bounce (NO atomics) ----
  float* sOut = (float*)&sH[0][0];   // 32 KB = 128 rows x 64 cols fp32
  #pragma unroll
  for (int h = 0; h < 2; ++h) {
    __syncthreads();                 // sH readers done / previous half stored
    #pragma unroll
    for (int r = 0; r < 4; ++r) {
      #pragma unroll
      for (int tt = 0; tt < 4; ++tt) {
        sOut[(wave * 16 + rowmap[r]) * 64 + tt * 16 + colmap[r]] =
            acc[h * 4 + tt][r];
      }
    }
    __syncthreads();
    #pragma unroll
    for (int i = 0; i < 4; ++i) {
      const int v = i * 512 + tid;          // f32x4 index, 2048 total
      const int rl = v >> 4, c4 = v & 15;   // 16 f32x4 per 64-col row
      *(f32x4*)&part[((size_t)CB * NN + rowbase + rl) * FOUT + h * 64 + c4 * 4] =
          ((const f32x4*)sOut)[v];
    }
  }
  // den partials: plain stores
  if (m == 0) {
    #pragma unroll
    for (int r = 0; r < 4; ++r)
      denp[(size_t)CB * NN + rowbase + wave * 16 + rowmap[r]] = den[r];
  }
}

// ---------------------------------------------------------------------------
// k_fin: out = (sum_cb part) / (sum_cb denp) + bias
// ---------------------------------------------------------------------------
__global__ __launch_bounds__(256) void k_fin(const float* __restrict__ part,
                                             const float* __restrict__ denp,
                                             const float* __restrict__ bias,
                                             float* __restrict__ out) {
  const int i4 = blockIdx.x * 256 + threadIdx.x;  // f32x4 index over out
  const int rowi = i4 >> 5;                       // 32 f32x4 per row
  const int f = (i4 & 31) * 4;
  float den = 0.f;
  f32x4 s = {0.f, 0.f, 0.f, 0.f};
  #pragma unroll
  for (int cb = 0; cb < 8; ++cb) {
    den += denp[(size_t)cb * NN + rowi];
    f32x4 p = *(const f32x4*)&part[((size_t)cb * NN + rowi) * FOUT + f];
    s[0] += p[0]; s[1] += p[1]; s[2] += p[2]; s[3] += p[3];
  }
  const float inv = 1.0f / den;
  f32x4 b = *(const f32x4*)(bias + f);
  f32x4 v = {s[0] * inv + b[0], s[1] * inv + b[1],
             s[2] * inv + b[2], s[3] * inv + b[3]};
  *(f32x4*)(out + (size_t)rowi * FOUT + f) = v;
}

// ---------------------------------------------------------------------------
extern "C" void kernel_launch(void* const* d_in, const int* in_sizes, int n_in,
                              void* d_out, int out_size, void* d_ws, size_t ws_size,
                              hipStream_t stream) {
  const float* x    = (const float*)d_in[0];
  const int*   adj  = (const int*)d_in[1];
  const float* W    = (const float*)d_in[2];
  const float* a1   = (const float*)d_in[3];
  const float* a2   = (const float*)d_in[4];
  const float* bias = (const float*)d_in[5];
  float* out = (float*)d_out;

  char* ws = (char*)d_ws;
  unsigned short* ht = (unsigned short*)ws;                            // 2 MB
  float* Etab = (float*)(ws + (size_t)2 * 1024 * 1024);                // 64 KB
  unsigned short* FbfF =
      (unsigned short*)(ws + (size_t)2 * 1024 * 1024 + 64 * 1024);     // 16 KB
  unsigned short* FbfF2 = FbfF + NN;                                   // 16 KB
  float* part = (float*)(ws + (size_t)4 * 1024 * 1024);                // 32 MB
  float* denp = (float*)(ws + (size_t)36 * 1024 * 1024);               // 256 KB

  k_hw<<<NN / 8, 256, 0, stream>>>(x, W, a1, a2, ht, Etab, FbfF, FbfF2);
  k_gat<<<512, 512, 0, stream>>>(adj, ht, Etab, FbfF, FbfF2, part, denp);
  k_fin<<<(NN * FOUT / 4) / 256, 256, 0, stream>>>(part, denp, bias, out);
}

// Round 10
// 433.945 us; speedup vs baseline: 1.1266x; 1.1266x over previous
//
#include <hip/hip_runtime.h>
#include <cstdint>
#include <cstddef>

#define NN 8192
#define FIN 256
#define FOUT 128
#define SLOPE 0.2f
#define SHIFT 8.0f

typedef float f32x4 __attribute__((ext_vector_type(4)));
typedef __bf16 bf16x8 __attribute__((ext_vector_type(8)));
typedef int i32x4 __attribute__((ext_vector_type(4)));
typedef unsigned int u32x4 __attribute__((ext_vector_type(4)));

__device__ __forceinline__ unsigned short f2bf(float f) {
  return __builtin_bit_cast(unsigned short, (__bf16)f);
}

// async global->LDS DMA; LDS dest = wave-uniform base + lane*16; per-lane src
__device__ __forceinline__ void async_cp16(void* lds, const void* g) {
  __builtin_amdgcn_global_load_lds(
      (const __attribute__((address_space(1))) void*)g,
      (__attribute__((address_space(3))) void*)lds, 16, 0, 0);
}

// ---------------------------------------------------------------------------
// Kernel A: h = x @ W (fp32 acc) -> ht[FOUT][NN] bf16 (transposed), fused
// s-reductions + exp tables. Unchanged.
// ---------------------------------------------------------------------------
__global__ __launch_bounds__(256, 4) void k_hw(const float* __restrict__ x,
                                               const float* __restrict__ W,
                                               const float* __restrict__ a1,
                                               const float* __restrict__ a2,
                                               unsigned short* __restrict__ ht,
                                               float* __restrict__ Etab,
                                               unsigned short* __restrict__ FbfF,
                                               unsigned short* __restrict__ FbfF2) {
  __shared__ float xs[8][256];
  __shared__ unsigned short tile[128][8];   // [f][row]
  const int tid = threadIdx.x;
  const int rowbase = blockIdx.x * 8;

  #pragma unroll
  for (int it = 0; it < 2; ++it) {
    int fi = it * 1024 + tid * 4;
    int r = fi >> 8, k = fi & 255;
    *(f32x4*)&xs[r][k] = *(const f32x4*)(x + (size_t)(rowbase + r) * FIN + k);
  }
  __syncthreads();

  const int r = tid >> 5;    // 0..7
  const int cg = tid & 31;   // cols cg*4..cg*4+3
  f32x4 acc = {0.f, 0.f, 0.f, 0.f};

  #pragma unroll 8
  for (int k = 0; k < FIN; ++k) {
    f32x4 wv = *(const f32x4*)(W + k * FOUT + cg * 4);
    float xv = xs[r][k];
    acc[0] += xv * wv[0];
    acc[1] += xv * wv[1];
    acc[2] += xv * wv[2];
    acc[3] += xv * wv[3];
  }

  #pragma unroll
  for (int c = 0; c < 4; ++c) tile[cg * 4 + c][r] = f2bf(acc[c]);

  f32x4 av1 = *(const f32x4*)(a1 + cg * 4);
  f32x4 av2 = *(const f32x4*)(a2 + cg * 4);
  float s1 = acc[0] * av1[0] + acc[1] * av1[1] + acc[2] * av1[2] + acc[3] * av1[3];
  float s2 = acc[0] * av2[0] + acc[1] * av2[1] + acc[2] * av2[2] + acc[3] * av2[3];
  #pragma unroll
  for (int off = 16; off > 0; off >>= 1) {
    s1 += __shfl_xor(s1, off, 64);
    s2 += __shfl_xor(s2, off, 64);
  }
  if (cg == 0) {
    const int row = rowbase + r;
    float c0 = s1 + SHIFT;
    float c = fmaxf(c0, SLOPE * c0);
    Etab[(size_t)row * 2]     = __expf(s1 - c);
    Etab[(size_t)row * 2 + 1] = __expf(SLOPE * s1 - c);
    FbfF[row]  = f2bf(__expf(s2));
    FbfF2[row] = f2bf(__expf(SLOPE * s2));
  }
  __syncthreads();

  if (tid < 128) {
    u32x4 v = *(const u32x4*)&tile[tid][0];
    *(u32x4*)(ht + (size_t)tid * NN + rowbase) = v;
  }
}

// ---------------------------------------------------------------------------
// Kernel B: fused masked-softmax aggregation, v18.
// v17 DIAGNOSTIC RESULT (k_gat finally visible at 2x loop = 181 us):
// VALUBusy 30%, MfmaUtil 8.5%, HBM 21%, conflicts negligible -> the
// pre-committed "latency/phase-overhead-bound" branch. Per-chunk wall
// 13,630 cy vs ~5,250 cy of per-SIMD busy work: ~60% of every chunk is
// dead time on ALL pipes. Cause: 8 waves per block in barrier lockstep
// with only 2 blocks/CU (grid 512 = the cap) to fill each other's stalls.
// v18 = 16-way column split: grid 1024 = 64 rowgroups x 16 colblocks
// -> 4 blocks/CU (LDS 35.3KB x4 = 141KB fits; VGPR 60 <= 64 keeps
// 8 waves/SIMD). 4 independent barrier domains per CU fill the idle 60%.
// Totals unchanged (adj 268 MB, ht 134 MB - splits with columns).
// Diagnostic rep-loop reverted. Partials now 16-way; k_fin reduces 16.
// ---------------------------------------------------------------------------
__global__ __launch_bounds__(512, 4) void k_gat(const int* __restrict__ adj,
                                                const unsigned short* __restrict__ ht,
                                                const float* __restrict__ Etab,
                                                const unsigned short* __restrict__ FbfF,
                                                const unsigned short* __restrict__ FbfF2,
                                                float* __restrict__ part,
                                                float* __restrict__ denp) {
  __shared__ unsigned short sH[2][128 * 64]; // 32 KB : ht, slot s holds group s^(f&7)
  __shared__ unsigned int sAp[2][128][2];    // 2 KB  : [buf][local row][word]
  __shared__ unsigned short sF[2][128];      // 512 B : [0,64)=F plane, [64,128)=F2

  const int tid = threadIdx.x;
  const int wave = tid >> 6;                 // 0..7, owns rows 16w..16w+15
  const int lane = tid & 63;
  const int quad = lane >> 4;
  const int m = lane & 15;                   // A-row label within wave's 16
  const int rowbase = (int)(blockIdx.x >> 4) * 128;
  const int CB = (int)(blockIdx.x & 15);
  const int colbase = CB * 512;
  const int row = rowbase + wave * 16 + m;

  // ---- runtime layout probes (exact in bf16/fp32) ----
  bf16x8 pm, pinv, pones;
  #pragma unroll
  for (int jj = 0; jj < 8; ++jj) {
    pm[jj] = (__bf16)(float)m;
    pinv[jj] = (__bf16)0.03125f;
    pones[jj] = (__bf16)1.0f;
  }
  f32x4 z = {0.f, 0.f, 0.f, 0.f};
  f32x4 rp = __builtin_amdgcn_mfma_f32_16x16x32_bf16(pm, pinv, z, 0, 0, 0);
  f32x4 cp = __builtin_amdgcn_mfma_f32_16x16x32_bf16(pinv, pm, z, 0, 0, 0);
  int rowmap[4], colmap[4];
  #pragma unroll
  for (int r = 0; r < 4; ++r) {
    rowmap[r] = ((int)(rp[r] + 0.5f)) & 15;
    colmap[r] = ((int)(cp[r] + 0.5f)) & 15;
  }

  const float E  = Etab[(size_t)row * 2];
  const float E2 = Etab[(size_t)row * 2 + 1];

  f32x4 acc[8];
  #pragma unroll
  for (int t = 0; t < 8; ++t) acc[t] = z;
  f32x4 den = z;

  // ---- adj raw source + register pipeline ----
  const int* adjRow = adj + (size_t)(rowbase + wave * 16) * NN + colbase + lane;
  int aregs[16];
  auto loadA = [&](int c) {            // 16 coalesced scalar loads (256 B/instr)
    #pragma unroll
    for (int r = 0; r < 16; ++r)
      aregs[r] = adjRow[(size_t)r * NN + c * 64];
  };
  auto packA = [&](int b) {            // ballot-pack regs -> sAp[b]
    #pragma unroll
    for (int r = 0; r < 16; ++r) {
      const unsigned long long mk = __ballot(aregs[r] != 0);
      if (lane == 0)
        *(unsigned long long*)&sAp[b][wave * 16 + r][0] = mk;
    }
  };

  // ---- ht / F DMA source pointers ----
  const unsigned short* srcH[2];
  #pragma unroll
  for (int il = 0; il < 2; ++il) {
    const int i = wave * 2 + il;
    const int f = i * 8 + (lane >> 3);
    const int g = (lane & 7) ^ (lane >> 3);
    srcH[il] = ht + (size_t)f * NN + colbase + g * 8;
  }
  const unsigned short* srcF = nullptr;
  if (wave == 1) {
    srcF = (lane < 8) ? (FbfF + colbase + lane * 8)
                      : (FbfF2 + colbase + (lane - 8) * 8);
  }

  auto stage = [&](int b, int c) {
    #pragma unroll
    for (int il = 0; il < 2; ++il)
      async_cp16(&sH[b][(wave * 2 + il) * 512], srcH[il] + c * 64);
    if (wave == 1 && lane < 16) async_cp16(&sF[b][0], srcF + c * 64);
  };

  auto compute = [&](int cs) {
    #pragma unroll
    for (int k32 = 0; k32 < 2; ++k32) {
      const unsigned int word = sAp[cs][wave * 16 + m][k32];
      const unsigned int byt = (word >> (quad * 8)) & 0xffu;
      const int jl = k32 * 32 + quad * 8;
      u32x4 Fq = *(const u32x4*)&sF[cs][jl];        // 8 bf16 F
      u32x4 Gq = *(const u32x4*)&sF[cs][64 + jl];   // 8 bf16 F2

      bf16x8 af;
      #pragma unroll
      for (int p = 0; p < 4; ++p) {
        const unsigned fp = Fq[p], gp = Gq[p];
        const float Flo = __builtin_bit_cast(float, fp << 16);
        const float Fhi = __builtin_bit_cast(float, fp & 0xffff0000u);
        const float Glo = __builtin_bit_cast(float, gp << 16);
        const float Ghi = __builtin_bit_cast(float, gp & 0xffff0000u);
        const float wlo = fmaxf(E * Flo, E2 * Glo);
        const float whi = fmaxf(E * Fhi, E2 * Ghi);
        af[p * 2]     = (byt & (1u << (p * 2)))     ? (__bf16)wlo : (__bf16)0.0f;
        af[p * 2 + 1] = (byt & (1u << (p * 2 + 1))) ? (__bf16)whi : (__bf16)0.0f;
      }

      // ht frags: tile t, slot s = (4k32+quad) ^ (m&7); same af for all 8 t
      const int s0 = (k32 * 4 + quad) ^ (m & 7);
      #pragma unroll
      for (int t = 0; t < 8; ++t) {
        bf16x8 bt = __builtin_bit_cast(bf16x8,
            *(const u32x4*)&sH[cs][(t * 16 + m) * 64 + s0 * 8]);
        acc[t] = __builtin_amdgcn_mfma_f32_16x16x32_bf16(af, bt, acc[t], 0, 0, 0);
      }
      den = __builtin_amdgcn_mfma_f32_16x16x32_bf16(af, pones, den, 0, 0, 0);
    }
  };

  // ---- prologue: pack chunk 0, preload regs for chunk 1, DMA chunk 0 ----
  loadA(0);       // compiler inserts the vmcnt wait before the ballots
  packA(0);
  loadA(1);
  stage(0, 0);

  // 8 chunks of 64 cols over this block's 512-col sixteenth; per phase:
  // barrier (drains DMA(c) + loads(c+1)) -> ballots(c+1) -> issue loads(c+2)
  // early -> DMA(c+1) -> compute(c).
  #pragma unroll 1
  for (int c = 0; c < 8; ++c) {
    const int cs = c & 1, ns = cs ^ 1;
    __syncthreads();
    if (c + 1 < 8) {
      packA(ns);                          // regs -> sAp[ns] (chunk c+1)
      loadA(c + 2 < 8 ? c + 2 : 7);       // issue next loads (dead at tail)
      stage(ns, c + 1);                   // ht/F DMA chunk c+1
    }
    compute(cs);                          // chunk c
  }

  // ---- epilogue: coalesced partial stores via LDS bounce (NO atomics) ----
  float* sOut = (float*)&sH[0][0];   // 32 KB = 128 rows x 64 cols fp32
  #pragma unroll
  for (int h = 0; h < 2; ++h) {
    __syncthreads();                 // sH readers done / previous half stored
    #pragma unroll
    for (int r = 0; r < 4; ++r) {
      #pragma unroll
      for (int tt = 0; tt < 4; ++tt) {
        sOut[(wave * 16 + rowmap[r]) * 64 + tt * 16 + colmap[r]] =
            acc[h * 4 + tt][r];
      }
    }
    __syncthreads();
    #pragma unroll
    for (int i = 0; i < 4; ++i) {
      const int v = i * 512 + tid;          // f32x4 index, 2048 total
      const int rl = v >> 4, c4 = v & 15;   // 16 f32x4 per 64-col row
      *(f32x4*)&part[((size_t)CB * NN + rowbase + rl) * FOUT + h * 64 + c4 * 4] =
          ((const f32x4*)sOut)[v];
    }
  }
  // den partials: plain stores
  if (m == 0) {
    #pragma unroll
    for (int r = 0; r < 4; ++r)
      denp[(size_t)CB * NN + rowbase + wave * 16 + rowmap[r]] = den[r];
  }
}

// ---------------------------------------------------------------------------
// k_fin: out = (sum_cb part) / (sum_cb denp) + bias   (16 partials)
// ---------------------------------------------------------------------------
__global__ __launch_bounds__(256) void k_fin(const float* __restrict__ part,
                                             const float* __restrict__ denp,
                                             const float* __restrict__ bias,
                                             float* __restrict__ out) {
  const int i4 = blockIdx.x * 256 + threadIdx.x;  // f32x4 index over out
  const int rowi = i4 >> 5;                       // 32 f32x4 per row
  const int f = (i4 & 31) * 4;
  float den = 0.f;
  f32x4 s = {0.f, 0.f, 0.f, 0.f};
  #pragma unroll
  for (int cb = 0; cb < 16; ++cb) {
    den += denp[(size_t)cb * NN + rowi];
    f32x4 p = *(const f32x4*)&part[((size_t)cb * NN + rowi) * FOUT + f];
    s[0] += p[0]; s[1] += p[1]; s[2] += p[2]; s[3] += p[3];
  }
  const float inv = 1.0f / den;
  f32x4 b = *(const f32x4*)(bias + f);
  f32x4 v = {s[0] * inv + b[0], s[1] * inv + b[1],
             s[2] * inv + b[2], s[3] * inv + b[3]};
  *(f32x4*)(out + (size_t)rowi * FOUT + f) = v;
}

// ---------------------------------------------------------------------------
extern "C" void kernel_launch(void* const* d_in, const int* in_sizes, int n_in,
                              void* d_out, int out_size, void* d_ws, size_t ws_size,
                              hipStream_t stream) {
  const float* x    = (const float*)d_in[0];
  const int*   adj  = (const int*)d_in[1];
  const float* W    = (const float*)d_in[2];
  const float* a1   = (const float*)d_in[3];
  const float* a2   = (const float*)d_in[4];
  const float* bias = (const float*)d_in[5];
  float* out = (float*)d_out;

  char* ws = (char*)d_ws;
  unsigned short* ht = (unsigned short*)ws;                            // 2 MB
  float* Etab = (float*)(ws + (size_t)2 * 1024 * 1024);                // 64 KB
  unsigned short* FbfF =
      (unsigned short*)(ws + (size_t)2 * 1024 * 1024 + 64 * 1024);     // 16 KB
  unsigned short* FbfF2 = FbfF + NN;                                   // 16 KB
  float* part = (float*)(ws + (size_t)4 * 1024 * 1024);                // 64 MB
  float* denp = (float*)(ws + (size_t)68 * 1024 * 1024);               // 512 KB

  k_hw<<<NN / 8, 256, 0, stream>>>(x, W, a1, a2, ht, Etab, FbfF, FbfF2);
  k_gat<<<1024, 512, 0, stream>>>(adj, ht, Etab, FbfF, FbfF2, part, denp);
  k_fin<<<(NN * FOUT / 4) / 256, 256, 0, stream>>>(part, denp, bias, out);
}